// Round 9
// baseline (573.062 us; speedup 1.0000x reference)
//
#include <hip/hip_runtime.h>
#include <hip/hip_bf16.h>
#include <math.h>

#define BATCH 8
#define NPTS  1024
#define DIM   1024
#define HID   64
#define KNN   20
#define NMAT  16
#define KPACK 3072   // 3 bf16 segments stored contiguously per row: k = seg*1024 + d

typedef __attribute__((ext_vector_type(8))) short short8;
typedef __attribute__((ext_vector_type(4))) float floatx4;

__device__ __forceinline__ const float* mat_base(const float* f1, const float* f2, int m) {
    return (m < BATCH) ? (f1 + (size_t)m * NPTS * DIM)
                       : (f2 + (size_t)(m - BATCH) * NPTS * DIM);
}

__device__ __forceinline__ unsigned short f2bf_bits(float v) {
    __hip_bfloat16 h = __float2bfloat16(v);   // RNE
    return *(unsigned short*)&h;
}
__device__ __forceinline__ float bfbits2f(unsigned short b) {
    union { unsigned u; float f; } c; c.u = ((unsigned)b) << 16; return c.f;
}

// ---------------- K1: 3-way bf16 split (segments packed per row) + squared norms ----------------
__global__ __launch_bounds__(256) void split_kernel(const float* __restrict__ f1,
                                                    const float* __restrict__ f2,
                                                    unsigned short* __restrict__ H,
                                                    float* __restrict__ sq) {
    int tid = threadIdx.x;
    int wave = tid >> 6, lane = tid & 63;
    int row = blockIdx.x * 4 + wave;              // 0..16383 = m*NPTS + i
    int m = row >> 10, i = row & (NPTS - 1);
    const float* fr = mat_base(f1, f2, m) + (size_t)i * DIM;
    unsigned short* Hr = H + (size_t)row * KPACK;
    float s = 0.f;
    #pragma unroll
    for (int t = 0; t < 4; ++t) {
        int idx = t * 256 + lane * 4;
        float4 v = *(const float4*)&fr[idx];
        s += v.x * v.x + v.y * v.y + v.z * v.z + v.w * v.w;
        unsigned short h1[4], h2[4], h3[4];
        float vv[4] = {v.x, v.y, v.z, v.w};
        #pragma unroll
        for (int c = 0; c < 4; ++c) {
            unsigned short b1 = f2bf_bits(vv[c]);
            float r1 = vv[c] - bfbits2f(b1);
            unsigned short b2 = f2bf_bits(r1);
            float r2 = r1 - bfbits2f(b2);
            unsigned short b3 = f2bf_bits(r2);
            h1[c] = b1; h2[c] = b2; h3[c] = b3;
        }
        *(ushort4*)&Hr[idx]        = *(ushort4*)&h1[0];
        *(ushort4*)&Hr[1024 + idx] = *(ushort4*)&h2[0];
        *(ushort4*)&Hr[2048 + idx] = *(ushort4*)&h3[0];
    }
    #pragma unroll
    for (int o = 32; o > 0; o >>= 1) s += __shfl_down(s, o);
    if (lane == 0) sq[row] = s;
}

// ---------------- K2: Gram -> squared distances via bf16 MFMA ----------------
// 128x128 upper-triangle tiles, mirror stores; XCD interleave of 2 matrices.
// Two staging passes keep LDS at 32 KB real (-> >=3 blocks/CU; all 72 blocks
// per XCD co-resident, no ragged tail — R7's 48KB block rounded to 64KB and
// ran 2/CU with an 8-block tail = 2x runtime):
//   pass 0 stages segs {h1,h2}: products (0,0),(1,0),(0,1),(1,1)
//   pass 1 stages segs {h1,h3}: products (2,0),(0,2)
// Accumulation reassociated across passes (~1e-7 on dist; tolerated since R6).
__global__ __launch_bounds__(256, 3) void gram_mfma_kernel(const unsigned short* __restrict__ H,
                                                           const float* __restrict__ sq,
                                                           float* __restrict__ dist) {
    int bid = blockIdx.x;
    int xcd = bid & 7;
    int g = bid >> 3;                 // 0..71
    int m = xcd + 8 * (g & 1);        // interleave this XCD's two matrices
    int t = g >> 1;                   // 0..35
    int bi = 0;
    { int a = t; while (a >= 8 - bi) { a -= 8 - bi; ++bi; } t = a; }
    int bj = bi + t;
    int ti = bi << 7, tj = bj << 7;

    const unsigned short* Hm = H + (size_t)m * NPTS * KPACK;

    // chunk cl = segl*8 + rowblk ; each chunk: [lane(64)][8 shorts] = 1KB (16 rows x 32 k)
    __shared__ __align__(16) unsigned short Asl[16 * 512];   // 16 KB (2 segs x 8 rowblocks)
    __shared__ __align__(16) unsigned short Bsl[16 * 512];   // 16 KB

    int tid = threadIdx.x;
    int w = tid >> 6, lane = tid & 63;
    int wi = w >> 1, wj = w & 1;
    int r16 = lane & 15, kc = lane >> 4;

    floatx4 acc[4][4];
    #pragma unroll
    for (int a = 0; a < 4; ++a)
        #pragma unroll
        for (int b = 0; b < 4; ++b) acc[a][b] = (floatx4)0.f;

    // ---- pass 0: segs {0,1} -> products (0,0),(1,0),(0,1),(1,1) ----
    for (int kk = 0; kk < 1024; kk += 32) {
        __syncthreads();
        #pragma unroll
        for (int c = 0; c < 8; ++c) {
            int ca = w * 8 + c;              // 0..31 ; wave-uniform A/B split
            int isB = ca >= 16;
            int cl = ca & 15;                // 0..15
            int segl = cl >> 3;              // 0..1 -> global seg 0/1
            int rb  = cl & 7;
            size_t koff = ((size_t)segl << 10) + kk + kc * 8;
            int baseRow = (isB ? tj : ti) + rb * 16 + r16;
            const unsigned short* gp = Hm + (size_t)baseRow * KPACK + koff;
            unsigned short* lp = (isB ? Bsl : Asl) + cl * 512;
            __builtin_amdgcn_global_load_lds(
                (const __attribute__((address_space(1))) void*)gp,
                (__attribute__((address_space(3))) void*)lp, 16, 0, 0);
        }
        __syncthreads();
        short8 af[2][4], bf[2][4];
        #pragma unroll
        for (int s = 0; s < 2; ++s)
            #pragma unroll
            for (int a = 0; a < 4; ++a) {
                af[s][a] = *(const short8*)&Asl[(s * 8 + wi * 4 + a) * 512 + lane * 8];
                bf[s][a] = *(const short8*)&Bsl[(s * 8 + wj * 4 + a) * 512 + lane * 8];
            }
        #pragma unroll
        for (int sb = 0; sb < 2; ++sb)
            #pragma unroll
            for (int sa = 0; sa < 2; ++sa)
                #pragma unroll
                for (int a = 0; a < 4; ++a)
                    #pragma unroll
                    for (int b = 0; b < 4; ++b)
                        acc[a][b] = __builtin_amdgcn_mfma_f32_16x16x32_bf16(af[sa][a], bf[sb][b], acc[a][b], 0, 0, 0);
    }

    // ---- pass 1: segs {0,2} -> products (2,0),(0,2) ----
    for (int kk = 0; kk < 1024; kk += 32) {
        __syncthreads();
        #pragma unroll
        for (int c = 0; c < 8; ++c) {
            int ca = w * 8 + c;
            int isB = ca >= 16;
            int cl = ca & 15;
            int segl = cl >> 3;              // 0..1 -> global seg 0/2
            int rb  = cl & 7;
            size_t koff = ((size_t)(segl ? 2 : 0) << 10) + kk + kc * 8;
            int baseRow = (isB ? tj : ti) + rb * 16 + r16;
            const unsigned short* gp = Hm + (size_t)baseRow * KPACK + koff;
            unsigned short* lp = (isB ? Bsl : Asl) + cl * 512;
            __builtin_amdgcn_global_load_lds(
                (const __attribute__((address_space(1))) void*)gp,
                (__attribute__((address_space(3))) void*)lp, 16, 0, 0);
        }
        __syncthreads();
        short8 af[2][4], bf[2][4];
        #pragma unroll
        for (int s = 0; s < 2; ++s)
            #pragma unroll
            for (int a = 0; a < 4; ++a) {
                af[s][a] = *(const short8*)&Asl[(s * 8 + wi * 4 + a) * 512 + lane * 8];
                bf[s][a] = *(const short8*)&Bsl[(s * 8 + wj * 4 + a) * 512 + lane * 8];
            }
        #pragma unroll
        for (int a = 0; a < 4; ++a)
            #pragma unroll
            for (int b = 0; b < 4; ++b)
                acc[a][b] = __builtin_amdgcn_mfma_f32_16x16x32_bf16(af[1][a], bf[0][b], acc[a][b], 0, 0, 0);
        #pragma unroll
        for (int a = 0; a < 4; ++a)
            #pragma unroll
            for (int b = 0; b < 4; ++b)
                acc[a][b] = __builtin_amdgcn_mfma_f32_16x16x32_bf16(af[0][a], bf[1][b], acc[a][b], 0, 0, 0);
    }

    const float* sqm = sq + m * NPTS;
    #pragma unroll
    for (int a = 0; a < 4; ++a) {
        int i0 = ti + wi * 64 + a * 16 + (lane >> 4) * 4;
        #pragma unroll
        for (int b = 0; b < 4; ++b) {
            int j = tj + wj * 64 + b * 16 + (lane & 15);
            float sqj = sqm[j];
            #pragma unroll
            for (int r = 0; r < 4; ++r) {
                int i = i0 + r;
                float v = sqm[i] + sqj - 2.f * acc[a][b][r];
                if (i == j) v += 1e10f;
                dist[((size_t)m * NPTS + i) * NPTS + j] = v;
                if (bi != bj) dist[((size_t)m * NPTS + j) * NPTS + i] = v;
            }
        }
    }
}

// ---------------- K3: top-k (k=20 smallest), one wave per row, all-register ----------------
__global__ __launch_bounds__(256) void topk_kernel(const float* __restrict__ dist,
                                                   int* __restrict__ knn_idx) {
    int tid = threadIdx.x;
    int wave = tid >> 6, lane = tid & 63;
    int row = blockIdx.x * 4 + wave;
    const float* d = dist + (size_t)row * NPTS;
    float v[16];
    #pragma unroll
    for (int s = 0; s < 16; ++s) v[s] = d[s * 64 + lane];
    int myj = 0;
    for (int sel = 0; sel < KNN; ++sel) {
        float bv = v[0]; int bs = 0;
        #pragma unroll
        for (int s = 1; s < 16; ++s)
            if (v[s] < bv) { bv = v[s]; bs = s; }   // ascending s: lowest j locally on ties
        int bj = bs * 64 + lane;
        #pragma unroll
        for (int off = 1; off < 64; off <<= 1) {
            float ov = __shfl_xor(bv, off);
            int   oj = __shfl_xor(bj, off);
            if (ov < bv || (ov == bv && oj < bj)) { bv = ov; bj = oj; }
        }
        if ((bj & 63) == lane) v[bj >> 6] = 3e38f;  // owner clears
        if (lane == sel) myj = bj;
    }
    if (lane < KNN) knn_idx[(size_t)row * KNN + lane] = myj;
}

// ---------------- K4: y = f @ W1a (no bias/act). GIN layer-1 projected BEFORE aggregation ----------------
__global__ __launch_bounds__(256) void ymlp_kernel(const float* __restrict__ f1,
                                                   const float* __restrict__ f2,
                                                   const float* __restrict__ W,
                                                   float* __restrict__ y) {
    int row0 = blockIdx.x * 64;                 // 64-row blocks never straddle matrices
    int m = row0 >> 10;
    const float* A = mat_base(f1, f2, m) + (size_t)(row0 & (NPTS - 1)) * DIM;
    __shared__ float As[64][20];
    __shared__ float Ws[16][HID];
    int tid = threadIdx.x;
    int ty = tid >> 4, tx = tid & 15;
    float acc[4][4];
    #pragma unroll
    for (int i = 0; i < 4; ++i)
        #pragma unroll
        for (int j = 0; j < 4; ++j) acc[i][j] = 0.f;
    for (int kk = 0; kk < DIM; kk += 16) {
        {
            int r = tid >> 2, c = (tid & 3) * 4;
            *(float4*)&As[r][c] = *(const float4*)&A[(size_t)r * DIM + kk + c];
        }
        {
            int d = tid >> 4, hh = (tid & 15) * 4;
            *(float4*)&Ws[d][hh] = *(const float4*)&W[(size_t)(kk + d) * HID + hh];
        }
        __syncthreads();
        #pragma unroll
        for (int k = 0; k < 16; ++k) {
            float a[4];
            #pragma unroll
            for (int ii = 0; ii < 4; ++ii) a[ii] = As[ty * 4 + ii][k];
            float4 w = *(const float4*)&Ws[k][tx * 4];
            #pragma unroll
            for (int ii = 0; ii < 4; ++ii) {
                acc[ii][0] += a[ii] * w.x;
                acc[ii][1] += a[ii] * w.y;
                acc[ii][2] += a[ii] * w.z;
                acc[ii][3] += a[ii] * w.w;
            }
        }
        __syncthreads();
    }
    #pragma unroll
    for (int ii = 0; ii < 4; ++ii)
        *(float4*)&y[(size_t)(row0 + ty * 4 + ii) * HID + tx * 4] = *(float4*)&acc[ii][0];
}

// ---------------- K5: t1 = relu(y_i + sum y_n + b1a); h1 = t1 @ W2a + b2a ----------------
__global__ __launch_bounds__(256) void t1h1_kernel(const float* __restrict__ y,
                                                   const int* __restrict__ knn_idx,
                                                   const float* __restrict__ W,
                                                   const float* __restrict__ bias1,
                                                   const float* __restrict__ bias2,
                                                   float* __restrict__ h1) {
    int row0 = blockIdx.x * 64;
    int m = row0 >> 10;
    __shared__ int nb[64 * KNN];
    __shared__ float t1s[64][65];
    __shared__ float Ws[64][HID];
    __shared__ float b1s[HID], b2s[HID];
    int tid = threadIdx.x;
    for (int k = tid; k < 64 * KNN; k += 256) nb[k] = knn_idx[(size_t)row0 * KNN + k];
    for (int k = tid; k < 64 * HID; k += 256) Ws[k >> 6][k & 63] = W[k];
    if (tid < HID) { b1s[tid] = bias1[tid]; b2s[tid] = bias2[tid]; }
    __syncthreads();
    {
        int r = tid >> 2, c0 = (tid & 3) * 16;
        const float* yr = y + (size_t)(row0 + r) * HID + c0;
        float4 a[4];
        #pragma unroll
        for (int q = 0; q < 4; ++q) a[q] = *(const float4*)&yr[q * 4];
        const float* ym = y + (size_t)(m << 10) * HID;
        #pragma unroll
        for (int t = 0; t < KNN; ++t) {
            const float* yn = ym + (size_t)nb[r * KNN + t] * HID + c0;
            #pragma unroll
            for (int q = 0; q < 4; ++q) {
                float4 v = *(const float4*)&yn[q * 4];
                a[q].x += v.x; a[q].y += v.y; a[q].z += v.z; a[q].w += v.w;
            }
        }
        #pragma unroll
        for (int q = 0; q < 4; ++q) {
            int c = c0 + q * 4;
            t1s[r][c + 0] = fmaxf(a[q].x + b1s[c + 0], 0.f);
            t1s[r][c + 1] = fmaxf(a[q].y + b1s[c + 1], 0.f);
            t1s[r][c + 2] = fmaxf(a[q].z + b1s[c + 2], 0.f);
            t1s[r][c + 3] = fmaxf(a[q].w + b1s[c + 3], 0.f);
        }
    }
    __syncthreads();
    int ty = tid >> 4, tx = tid & 15;
    float acc[4][4];
    #pragma unroll
    for (int i = 0; i < 4; ++i)
        #pragma unroll
        for (int j = 0; j < 4; ++j) acc[i][j] = 0.f;
    #pragma unroll
    for (int k = 0; k < HID; ++k) {
        float a[4];
        #pragma unroll
        for (int ii = 0; ii < 4; ++ii) a[ii] = t1s[ty * 4 + ii][k];
        float4 w = *(const float4*)&Ws[k][tx * 4];
        #pragma unroll
        for (int ii = 0; ii < 4; ++ii) {
            acc[ii][0] += a[ii] * w.x;
            acc[ii][1] += a[ii] * w.y;
            acc[ii][2] += a[ii] * w.z;
            acc[ii][3] += a[ii] * w.w;
        }
    }
    #pragma unroll
    for (int ii = 0; ii < 4; ++ii) {
        float o[4];
        #pragma unroll
        for (int jj = 0; jj < 4; ++jj) o[jj] = acc[ii][jj] + b2s[tx * 4 + jj];
        *(float4*)&h1[(size_t)(row0 + ty * 4 + ii) * HID + tx * 4] = *(float4*)&o[0];
    }
}

// ---------------- K6: hs = h1_i + sum h1_n; t2 = relu(hs@W1b+b1b); z = t2@W2b+b2b ----------------
__global__ __launch_bounds__(256) void t2z_kernel(const float* __restrict__ h1,
                                                  const int* __restrict__ knn_idx,
                                                  const float* __restrict__ W1,
                                                  const float* __restrict__ bias1,
                                                  const float* __restrict__ W2,
                                                  const float* __restrict__ bias2,
                                                  float* __restrict__ z) {
    int row0 = blockIdx.x * 64;
    int m = row0 >> 10;
    __shared__ int nb[64 * KNN];
    __shared__ float hs[64][65];
    __shared__ float t2s[64][65];
    __shared__ float Ws[64][HID];
    __shared__ float b1s[HID], b2s[HID];
    int tid = threadIdx.x;
    for (int k = tid; k < 64 * KNN; k += 256) nb[k] = knn_idx[(size_t)row0 * KNN + k];
    for (int k = tid; k < 64 * HID; k += 256) Ws[k >> 6][k & 63] = W1[k];
    if (tid < HID) { b1s[tid] = bias1[tid]; b2s[tid] = bias2[tid]; }
    __syncthreads();
    {
        int r = tid >> 2, c0 = (tid & 3) * 16;
        const float* hr = h1 + (size_t)(row0 + r) * HID + c0;
        float4 a[4];
        #pragma unroll
        for (int q = 0; q < 4; ++q) a[q] = *(const float4*)&hr[q * 4];
        const float* hm = h1 + (size_t)(m << 10) * HID;
        #pragma unroll
        for (int t = 0; t < KNN; ++t) {
            const float* hn = hm + (size_t)nb[r * KNN + t] * HID + c0;
            #pragma unroll
            for (int q = 0; q < 4; ++q) {
                float4 v = *(const float4*)&hn[q * 4];
                a[q].x += v.x; a[q].y += v.y; a[q].z += v.z; a[q].w += v.w;
            }
        }
        #pragma unroll
        for (int q = 0; q < 4; ++q) *(float4*)&hs[r][c0 + q * 4] = a[q];
    }
    __syncthreads();
    int ty = tid >> 4, tx = tid & 15;
    float acc[4][4];
    #pragma unroll
    for (int i = 0; i < 4; ++i)
        #pragma unroll
        for (int j = 0; j < 4; ++j) acc[i][j] = 0.f;
    #pragma unroll
    for (int k = 0; k < HID; ++k) {
        float a[4];
        #pragma unroll
        for (int ii = 0; ii < 4; ++ii) a[ii] = hs[ty * 4 + ii][k];
        float4 w = *(const float4*)&Ws[k][tx * 4];
        #pragma unroll
        for (int ii = 0; ii < 4; ++ii) {
            acc[ii][0] += a[ii] * w.x;
            acc[ii][1] += a[ii] * w.y;
            acc[ii][2] += a[ii] * w.z;
            acc[ii][3] += a[ii] * w.w;
        }
    }
    #pragma unroll
    for (int ii = 0; ii < 4; ++ii)
        #pragma unroll
        for (int jj = 0; jj < 4; ++jj)
            t2s[ty * 4 + ii][tx * 4 + jj] = fmaxf(acc[ii][jj] + b1s[tx * 4 + jj], 0.f);
    __syncthreads();
    for (int k = tid; k < 64 * HID; k += 256) Ws[k >> 6][k & 63] = W2[k];
    __syncthreads();
    #pragma unroll
    for (int i = 0; i < 4; ++i)
        #pragma unroll
        for (int j = 0; j < 4; ++j) acc[i][j] = 0.f;
    #pragma unroll
    for (int k = 0; k < HID; ++k) {
        float a[4];
        #pragma unroll
        for (int ii = 0; ii < 4; ++ii) a[ii] = t2s[ty * 4 + ii][k];
        float4 w = *(const float4*)&Ws[k][tx * 4];
        #pragma unroll
        for (int ii = 0; ii < 4; ++ii) {
            acc[ii][0] += a[ii] * w.x;
            acc[ii][1] += a[ii] * w.y;
            acc[ii][2] += a[ii] * w.z;
            acc[ii][3] += a[ii] * w.w;
        }
    }
    #pragma unroll
    for (int ii = 0; ii < 4; ++ii) {
        float o[4];
        #pragma unroll
        for (int jj = 0; jj < 4; ++jj) o[jj] = acc[ii][jj] + b2s[tx * 4 + jj];
        *(float4*)&z[(size_t)(row0 + ty * 4 + ii) * HID + tx * 4] = *(float4*)&o[0];
    }
}

// ---------------- K7: sim = z1 @ z2^T (64x64 tiles, K=64) ----------------
__global__ __launch_bounds__(256) void sim_kernel(const float* __restrict__ z,
                                                  float* __restrict__ logits) {
    int bid = blockIdx.x;
    int b = bid >> 8;
    int tile = bid & 255;
    int ti = (tile >> 4) << 6;
    int tj = (tile & 15) << 6;
    const float* z1 = z + (size_t)b * NPTS * HID;
    const float* z2 = z + (size_t)(BATCH + b) * NPTS * HID;
    __shared__ float Z1[64][68];
    __shared__ float Z2[64][68];
    int tid = threadIdx.x;
    #pragma unroll
    for (int i = 0; i < 4; ++i) {
        int l = tid + i * 256;
        int r = l >> 4, c = (l & 15) * 4;
        *(float4*)&Z1[r][c] = *(const float4*)&z1[(size_t)(ti + r) * HID + c];
        *(float4*)&Z2[r][c] = *(const float4*)&z2[(size_t)(tj + r) * HID + c];
    }
    __syncthreads();
    int ty = tid >> 4, tx = tid & 15;
    float acc[4][4];
    #pragma unroll
    for (int i = 0; i < 4; ++i)
        #pragma unroll
        for (int j = 0; j < 4; ++j) acc[i][j] = 0.f;
    #pragma unroll
    for (int h = 0; h < HID; ++h) {
        float a[4], bb[4];
        #pragma unroll
        for (int ii = 0; ii < 4; ++ii) { a[ii] = Z1[ty * 4 + ii][h]; bb[ii] = Z2[tx * 4 + ii][h]; }
        #pragma unroll
        for (int ii = 0; ii < 4; ++ii)
            #pragma unroll
            for (int jj = 0; jj < 4; ++jj)
                acc[ii][jj] += a[ii] * bb[jj];
    }
    #pragma unroll
    for (int ii = 0; ii < 4; ++ii) {
        float* dst = logits + ((size_t)b * NPTS + ti + ty * 4 + ii) * NPTS + tj + tx * 4;
        *(float4*)&dst[0] = *(float4*)&acc[ii][0];
    }
}

// ---------------- K8: row softmax ----------------
__global__ __launch_bounds__(256) void softmax_kernel(const float* __restrict__ logits,
                                                      float* __restrict__ out) {
    int row = blockIdx.x;                         // 0..8191
    const float* L = logits + (size_t)row * NPTS;
    __shared__ float buf[NPTS];
    __shared__ float red[8];
    int tid = threadIdx.x;
    int wave = tid >> 6, lane = tid & 63;
    float mx = -3e38f;
    #pragma unroll
    for (int s = 0; s < 4; ++s) {
        float v = L[tid + s * 256];
        buf[tid + s * 256] = v;
        mx = fmaxf(mx, v);
    }
    #pragma unroll
    for (int off = 32; off > 0; off >>= 1) mx = fmaxf(mx, __shfl_down(mx, off));
    if (lane == 0) red[wave] = mx;
    __syncthreads();
    mx = fmaxf(fmaxf(red[0], red[1]), fmaxf(red[2], red[3]));
    float sum = 0.f;
    #pragma unroll
    for (int s = 0; s < 4; ++s) {
        float e = expf(buf[tid + s * 256] - mx);
        buf[tid + s * 256] = e;
        sum += e;
    }
    #pragma unroll
    for (int off = 32; off > 0; off >>= 1) sum += __shfl_down(sum, off);
    if (lane == 0) red[4 + wave] = sum;
    __syncthreads();
    float inv = 1.f / (red[4] + red[5] + red[6] + red[7]);
    #pragma unroll
    for (int s = 0; s < 4; ++s)
        out[(size_t)row * NPTS + tid + s * 256] = buf[tid + s * 256] * inv;
}

extern "C" void kernel_launch(void* const* d_in, const int* in_sizes, int n_in,
                              void* d_out, int out_size, void* d_ws, size_t ws_size,
                              hipStream_t stream) {
    const float* f1  = (const float*)d_in[0];
    const float* f2  = (const float*)d_in[1];
    const float* W1a = (const float*)d_in[2];
    const float* b1a = (const float*)d_in[3];
    const float* W2a = (const float*)d_in[4];
    const float* b2a = (const float*)d_in[5];
    const float* W1b = (const float*)d_in[6];
    const float* b1b = (const float*)d_in[7];
    const float* W2b = (const float*)d_in[8];
    const float* b2b = (const float*)d_in[9];
    float* out = (float*)d_out;

    // workspace: H packed (100.7MB) | dist (67.1MB, reused as sim logits) | sq | kidx | y | h1 | z
    char* ws = (char*)d_ws;
    unsigned short* H = (unsigned short*)ws;
    float* dist = (float*)(ws + (size_t)NMAT * NPTS * KPACK * sizeof(unsigned short));
    float* sq   = dist + (size_t)NMAT * NPTS * NPTS;
    int*   kidx = (int*)(sq + NMAT * NPTS);
    float* ybuf = (float*)(kidx + NMAT * NPTS * KNN);
    float* h1b  = ybuf + (size_t)NMAT * NPTS * HID;
    float* zb   = h1b + (size_t)NMAT * NPTS * HID;

    split_kernel<<<NMAT * NPTS / 4, 256, 0, stream>>>(f1, f2, H, sq);
    gram_mfma_kernel<<<NMAT * 36, 256, 0, stream>>>(H, sq, dist);
    topk_kernel<<<NMAT * NPTS / 4, 256, 0, stream>>>(dist, kidx);
    ymlp_kernel<<<NMAT * NPTS / 64, 256, 0, stream>>>(f1, f2, W1a, ybuf);
    t1h1_kernel<<<NMAT * NPTS / 64, 256, 0, stream>>>(ybuf, kidx, W2a, b1a, b2a, h1b);
    t2z_kernel<<<NMAT * NPTS / 64, 256, 0, stream>>>(h1b, kidx, W1b, b1b, W2b, b2b, zb);
    sim_kernel<<<BATCH * 256, 256, 0, stream>>>(zb, dist);                      // dist := logits
    softmax_kernel<<<BATCH * NPTS, 256, 0, stream>>>(dist, out);
}

// Round 10
// 539.365 us; speedup vs baseline: 1.0625x; 1.0625x over previous
//
#include <hip/hip_runtime.h>
#include <hip/hip_bf16.h>
#include <math.h>

#define BATCH 8
#define NPTS  1024
#define DIM   1024
#define HID   64
#define KNN   20
#define NMAT  16
#define KPACK 3072   // 3 bf16 segments stored contiguously per row: k = seg*1024 + d

typedef __attribute__((ext_vector_type(8))) short short8;
typedef __attribute__((ext_vector_type(4))) float floatx4;

__device__ __forceinline__ const float* mat_base(const float* f1, const float* f2, int m) {
    return (m < BATCH) ? (f1 + (size_t)m * NPTS * DIM)
                       : (f2 + (size_t)(m - BATCH) * NPTS * DIM);
}

__device__ __forceinline__ unsigned short f2bf_bits(float v) {
    __hip_bfloat16 h = __float2bfloat16(v);   // RNE
    return *(unsigned short*)&h;
}
__device__ __forceinline__ float bfbits2f(unsigned short b) {
    union { unsigned u; float f; } c; c.u = ((unsigned)b) << 16; return c.f;
}

// ---------------- K1: FUSED 3-way bf16 split + squared norms + y = f @ W1a ----------------
// Reads each f element exactly once (was read twice by split_kernel + ymlp_kernel).
// H bits and y are bitwise-identical to the previous separate kernels; sq is
// reassociated (~1e-4, tolerance established empirically since R1).
__global__ __launch_bounds__(256) void split_ymlp_kernel(const float* __restrict__ f1,
                                                         const float* __restrict__ f2,
                                                         const float* __restrict__ W,
                                                         unsigned short* __restrict__ H,
                                                         float* __restrict__ sq,
                                                         float* __restrict__ y) {
    int row0 = blockIdx.x * 64;                 // 64-row blocks never straddle matrices
    int m = row0 >> 10;
    const float* A = mat_base(f1, f2, m) + (size_t)(row0 & (NPTS - 1)) * DIM;
    unsigned short* Hb = H + (size_t)row0 * KPACK;
    __shared__ float As[64][20];
    __shared__ float Ws[16][HID];
    int tid = threadIdx.x;
    int r = tid >> 2, cq = (tid & 3) * 4;       // fixed load assignment: row r, cols cq..cq+3
    int ty = tid >> 4, tx = tid & 15;
    float acc[4][4];
    #pragma unroll
    for (int i = 0; i < 4; ++i)
        #pragma unroll
        for (int j = 0; j < 4; ++j) acc[i][j] = 0.f;
    float sqp = 0.f;
    unsigned short* Hr = Hb + (size_t)r * KPACK + cq;

    for (int kk = 0; kk < DIM; kk += 16) {
        float4 a = *(const float4*)&A[(size_t)r * DIM + kk + cq];
        // ---- split (bitwise-identical to old split_kernel chain) ----
        {
            float vv[4] = {a.x, a.y, a.z, a.w};
            unsigned short h1[4], h2[4], h3[4];
            #pragma unroll
            for (int c = 0; c < 4; ++c) {
                unsigned short b1 = f2bf_bits(vv[c]);
                float r1 = vv[c] - bfbits2f(b1);
                unsigned short b2 = f2bf_bits(r1);
                float r2 = r1 - bfbits2f(b2);
                unsigned short b3 = f2bf_bits(r2);
                h1[c] = b1; h2[c] = b2; h3[c] = b3;
            }
            *(ushort4*)&Hr[kk]        = *(ushort4*)&h1[0];
            *(ushort4*)&Hr[1024 + kk] = *(ushort4*)&h2[0];
            *(ushort4*)&Hr[2048 + kk] = *(ushort4*)&h3[0];
            sqp += a.x * a.x + a.y * a.y + a.z * a.z + a.w * a.w;
        }
        // ---- GEMM staging (identical to old ymlp_kernel) ----
        *(float4*)&As[r][cq] = a;
        {
            int d = tid >> 4, hh = (tid & 15) * 4;
            *(float4*)&Ws[d][hh] = *(const float4*)&W[(size_t)(kk + d) * HID + hh];
        }
        __syncthreads();
        #pragma unroll
        for (int k = 0; k < 16; ++k) {
            float av[4];
            #pragma unroll
            for (int ii = 0; ii < 4; ++ii) av[ii] = As[ty * 4 + ii][k];
            float4 w = *(const float4*)&Ws[k][tx * 4];
            #pragma unroll
            for (int ii = 0; ii < 4; ++ii) {
                acc[ii][0] += av[ii] * w.x;
                acc[ii][1] += av[ii] * w.y;
                acc[ii][2] += av[ii] * w.z;
                acc[ii][3] += av[ii] * w.w;
            }
        }
        __syncthreads();
    }
    // sq: combine the 4 per-thread partials of each row (lanes 4r..4r+3 contiguous)
    sqp += __shfl_down(sqp, 1);
    sqp += __shfl_down(sqp, 2);
    if ((tid & 3) == 0) sq[row0 + r] = sqp;
    // y store (identical to old ymlp_kernel)
    #pragma unroll
    for (int ii = 0; ii < 4; ++ii)
        *(float4*)&y[(size_t)(row0 + ty * 4 + ii) * HID + tx * 4] = *(float4*)&acc[ii][0];
}

// ---------------- K2: Gram -> squared distances via bf16 MFMA (R7 verbatim: best 202us) ----------------
// Fused-segment K-loop: per BK=32 slice, stage all 3 segments of A and B once
// (48 KB LDS) and compute the 6 split products (segA+segB<=2) from them.
// 128x128 upper-triangle tiles, mirror stores; XCD interleave of 2 matrices.
__global__ __launch_bounds__(256) void gram_mfma_kernel(const unsigned short* __restrict__ H,
                                                        const float* __restrict__ sq,
                                                        float* __restrict__ dist) {
    int bid = blockIdx.x;
    int xcd = bid & 7;
    int g = bid >> 3;                 // 0..71
    int m = xcd + 8 * (g & 1);        // interleave this XCD's two matrices
    int t = g >> 1;                   // 0..35
    int bi = 0;
    { int a = t; while (a >= 8 - bi) { a -= 8 - bi; ++bi; } t = a; }
    int bj = bi + t;
    int ti = bi << 7, tj = bj << 7;

    const unsigned short* Hm = H + (size_t)m * NPTS * KPACK;

    // chunk ca = seg*8 + rowblk ; each chunk: [lane(64)][8 shorts] = 1KB (16 rows x 32 k)
    __shared__ __align__(16) unsigned short Asl[24 * 512];   // 24 KB
    __shared__ __align__(16) unsigned short Bsl[24 * 512];   // 24 KB

    int tid = threadIdx.x;
    int w = tid >> 6, lane = tid & 63;
    int wi = w >> 1, wj = w & 1;
    int r16 = lane & 15, kc = lane >> 4;

    floatx4 acc[4][4];
    #pragma unroll
    for (int a = 0; a < 4; ++a)
        #pragma unroll
        for (int b = 0; b < 4; ++b) acc[a][b] = (floatx4)0.f;

    for (int kk = 0; kk < 1024; kk += 32) {
        __syncthreads();
        #pragma unroll
        for (int c = 0; c < 6; ++c) {
            int ca = w * 6 + c;              // 0..23
            int seg = ca >> 3;               // 0..2
            int rb  = ca & 7;                // 0..7
            size_t koff = (size_t)(seg << 10) + kk + kc * 8;
            const unsigned short* ga = Hm + (size_t)(ti + rb * 16 + r16) * KPACK + koff;
            const unsigned short* gb = Hm + (size_t)(tj + rb * 16 + r16) * KPACK + koff;
            __builtin_amdgcn_global_load_lds(
                (const __attribute__((address_space(1))) void*)ga,
                (__attribute__((address_space(3))) void*)&Asl[ca * 512], 16, 0, 0);
            __builtin_amdgcn_global_load_lds(
                (const __attribute__((address_space(1))) void*)gb,
                (__attribute__((address_space(3))) void*)&Bsl[ca * 512], 16, 0, 0);
        }
        __syncthreads();
        short8 af[3][4];
        #pragma unroll
        for (int s = 0; s < 3; ++s)
            #pragma unroll
            for (int a = 0; a < 4; ++a)
                af[s][a] = *(const short8*)&Asl[(s * 8 + wi * 4 + a) * 512 + lane * 8];
        #pragma unroll
        for (int sb = 0; sb < 3; ++sb) {
            short8 bf[4];
            #pragma unroll
            for (int b = 0; b < 4; ++b)
                bf[b] = *(const short8*)&Bsl[(sb * 8 + wj * 4 + b) * 512 + lane * 8];
            #pragma unroll
            for (int sa = 0; sa < 3; ++sa) {
                if (sa + sb > 2) continue;   // products: (0,0),(1,0),(2,0),(0,1),(1,1),(0,2)
                #pragma unroll
                for (int a = 0; a < 4; ++a)
                    #pragma unroll
                    for (int b = 0; b < 4; ++b)
                        acc[a][b] = __builtin_amdgcn_mfma_f32_16x16x32_bf16(af[sa][a], bf[b], acc[a][b], 0, 0, 0);
            }
        }
    }

    const float* sqm = sq + m * NPTS;
    #pragma unroll
    for (int a = 0; a < 4; ++a) {
        int i0 = ti + wi * 64 + a * 16 + (lane >> 4) * 4;
        #pragma unroll
        for (int b = 0; b < 4; ++b) {
            int j = tj + wj * 64 + b * 16 + (lane & 15);
            float sqj = sqm[j];
            #pragma unroll
            for (int r = 0; r < 4; ++r) {
                int i = i0 + r;
                float v = sqm[i] + sqj - 2.f * acc[a][b][r];
                if (i == j) v += 1e10f;
                dist[((size_t)m * NPTS + i) * NPTS + j] = v;
                if (bi != bj) dist[((size_t)m * NPTS + j) * NPTS + i] = v;
            }
        }
    }
}

// ---------------- K3: top-k (k=20 smallest), one wave per row, all-register ----------------
__global__ __launch_bounds__(256) void topk_kernel(const float* __restrict__ dist,
                                                   int* __restrict__ knn_idx) {
    int tid = threadIdx.x;
    int wave = tid >> 6, lane = tid & 63;
    int row = blockIdx.x * 4 + wave;
    const float* d = dist + (size_t)row * NPTS;
    float v[16];
    #pragma unroll
    for (int s = 0; s < 16; ++s) v[s] = d[s * 64 + lane];
    int myj = 0;
    for (int sel = 0; sel < KNN; ++sel) {
        float bv = v[0]; int bs = 0;
        #pragma unroll
        for (int s = 1; s < 16; ++s)
            if (v[s] < bv) { bv = v[s]; bs = s; }   // ascending s: lowest j locally on ties
        int bj = bs * 64 + lane;
        #pragma unroll
        for (int off = 1; off < 64; off <<= 1) {
            float ov = __shfl_xor(bv, off);
            int   oj = __shfl_xor(bj, off);
            if (ov < bv || (ov == bv && oj < bj)) { bv = ov; bj = oj; }
        }
        if ((bj & 63) == lane) v[bj >> 6] = 3e38f;  // owner clears
        if (lane == sel) myj = bj;
    }
    if (lane < KNN) knn_idx[(size_t)row * KNN + lane] = myj;
}

// ---------------- K5: t1 = relu(y_i + sum y_n + b1a); h1 = t1 @ W2a + b2a ----------------
__global__ __launch_bounds__(256) void t1h1_kernel(const float* __restrict__ y,
                                                   const int* __restrict__ knn_idx,
                                                   const float* __restrict__ W,
                                                   const float* __restrict__ bias1,
                                                   const float* __restrict__ bias2,
                                                   float* __restrict__ h1) {
    int row0 = blockIdx.x * 64;
    int m = row0 >> 10;
    __shared__ int nb[64 * KNN];
    __shared__ float t1s[64][65];
    __shared__ float Ws[64][HID];
    __shared__ float b1s[HID], b2s[HID];
    int tid = threadIdx.x;
    for (int k = tid; k < 64 * KNN; k += 256) nb[k] = knn_idx[(size_t)row0 * KNN + k];
    for (int k = tid; k < 64 * HID; k += 256) Ws[k >> 6][k & 63] = W[k];
    if (tid < HID) { b1s[tid] = bias1[tid]; b2s[tid] = bias2[tid]; }
    __syncthreads();
    {
        int r = tid >> 2, c0 = (tid & 3) * 16;
        const float* yr = y + (size_t)(row0 + r) * HID + c0;
        float4 a[4];
        #pragma unroll
        for (int q = 0; q < 4; ++q) a[q] = *(const float4*)&yr[q * 4];
        const float* ym = y + (size_t)(m << 10) * HID;
        #pragma unroll
        for (int t = 0; t < KNN; ++t) {
            const float* yn = ym + (size_t)nb[r * KNN + t] * HID + c0;
            #pragma unroll
            for (int q = 0; q < 4; ++q) {
                float4 v = *(const float4*)&yn[q * 4];
                a[q].x += v.x; a[q].y += v.y; a[q].z += v.z; a[q].w += v.w;
            }
        }
        #pragma unroll
        for (int q = 0; q < 4; ++q) {
            int c = c0 + q * 4;
            t1s[r][c + 0] = fmaxf(a[q].x + b1s[c + 0], 0.f);
            t1s[r][c + 1] = fmaxf(a[q].y + b1s[c + 1], 0.f);
            t1s[r][c + 2] = fmaxf(a[q].z + b1s[c + 2], 0.f);
            t1s[r][c + 3] = fmaxf(a[q].w + b1s[c + 3], 0.f);
        }
    }
    __syncthreads();
    int ty = tid >> 4, tx = tid & 15;
    float acc[4][4];
    #pragma unroll
    for (int i = 0; i < 4; ++i)
        #pragma unroll
        for (int j = 0; j < 4; ++j) acc[i][j] = 0.f;
    #pragma unroll
    for (int k = 0; k < HID; ++k) {
        float a[4];
        #pragma unroll
        for (int ii = 0; ii < 4; ++ii) a[ii] = t1s[ty * 4 + ii][k];
        float4 w = *(const float4*)&Ws[k][tx * 4];
        #pragma unroll
        for (int ii = 0; ii < 4; ++ii) {
            acc[ii][0] += a[ii] * w.x;
            acc[ii][1] += a[ii] * w.y;
            acc[ii][2] += a[ii] * w.z;
            acc[ii][3] += a[ii] * w.w;
        }
    }
    #pragma unroll
    for (int ii = 0; ii < 4; ++ii) {
        float o[4];
        #pragma unroll
        for (int jj = 0; jj < 4; ++jj) o[jj] = acc[ii][jj] + b2s[tx * 4 + jj];
        *(float4*)&h1[(size_t)(row0 + ty * 4 + ii) * HID + tx * 4] = *(float4*)&o[0];
    }
}

// ---------------- K6: hs = h1_i + sum h1_n; t2 = relu(hs@W1b+b1b); z = t2@W2b+b2b ----------------
__global__ __launch_bounds__(256) void t2z_kernel(const float* __restrict__ h1,
                                                  const int* __restrict__ knn_idx,
                                                  const float* __restrict__ W1,
                                                  const float* __restrict__ bias1,
                                                  const float* __restrict__ W2,
                                                  const float* __restrict__ bias2,
                                                  float* __restrict__ z) {
    int row0 = blockIdx.x * 64;
    int m = row0 >> 10;
    __shared__ int nb[64 * KNN];
    __shared__ float hs[64][65];
    __shared__ float t2s[64][65];
    __shared__ float Ws[64][HID];
    __shared__ float b1s[HID], b2s[HID];
    int tid = threadIdx.x;
    for (int k = tid; k < 64 * KNN; k += 256) nb[k] = knn_idx[(size_t)row0 * KNN + k];
    for (int k = tid; k < 64 * HID; k += 256) Ws[k >> 6][k & 63] = W1[k];
    if (tid < HID) { b1s[tid] = bias1[tid]; b2s[tid] = bias2[tid]; }
    __syncthreads();
    {
        int r = tid >> 2, c0 = (tid & 3) * 16;
        const float* hr = h1 + (size_t)(row0 + r) * HID + c0;
        float4 a[4];
        #pragma unroll
        for (int q = 0; q < 4; ++q) a[q] = *(const float4*)&hr[q * 4];
        const float* hm = h1 + (size_t)(m << 10) * HID;
        #pragma unroll
        for (int t = 0; t < KNN; ++t) {
            const float* hn = hm + (size_t)nb[r * KNN + t] * HID + c0;
            #pragma unroll
            for (int q = 0; q < 4; ++q) {
                float4 v = *(const float4*)&hn[q * 4];
                a[q].x += v.x; a[q].y += v.y; a[q].z += v.z; a[q].w += v.w;
            }
        }
        #pragma unroll
        for (int q = 0; q < 4; ++q) *(float4*)&hs[r][c0 + q * 4] = a[q];
    }
    __syncthreads();
    int ty = tid >> 4, tx = tid & 15;
    float acc[4][4];
    #pragma unroll
    for (int i = 0; i < 4; ++i)
        #pragma unroll
        for (int j = 0; j < 4; ++j) acc[i][j] = 0.f;
    #pragma unroll
    for (int k = 0; k < HID; ++k) {
        float a[4];
        #pragma unroll
        for (int ii = 0; ii < 4; ++ii) a[ii] = hs[ty * 4 + ii][k];
        float4 w = *(const float4*)&Ws[k][tx * 4];
        #pragma unroll
        for (int ii = 0; ii < 4; ++ii) {
            acc[ii][0] += a[ii] * w.x;
            acc[ii][1] += a[ii] * w.y;
            acc[ii][2] += a[ii] * w.z;
            acc[ii][3] += a[ii] * w.w;
        }
    }
    #pragma unroll
    for (int ii = 0; ii < 4; ++ii)
        #pragma unroll
        for (int jj = 0; jj < 4; ++jj)
            t2s[ty * 4 + ii][tx * 4 + jj] = fmaxf(acc[ii][jj] + b1s[tx * 4 + jj], 0.f);
    __syncthreads();
    for (int k = tid; k < 64 * HID; k += 256) Ws[k >> 6][k & 63] = W2[k];
    __syncthreads();
    #pragma unroll
    for (int i = 0; i < 4; ++i)
        #pragma unroll
        for (int j = 0; j < 4; ++j) acc[i][j] = 0.f;
    #pragma unroll
    for (int k = 0; k < HID; ++k) {
        float a[4];
        #pragma unroll
        for (int ii = 0; ii < 4; ++ii) a[ii] = t2s[ty * 4 + ii][k];
        float4 w = *(const float4*)&Ws[k][tx * 4];
        #pragma unroll
        for (int ii = 0; ii < 4; ++ii) {
            acc[ii][0] += a[ii] * w.x;
            acc[ii][1] += a[ii] * w.y;
            acc[ii][2] += a[ii] * w.z;
            acc[ii][3] += a[ii] * w.w;
        }
    }
    #pragma unroll
    for (int ii = 0; ii < 4; ++ii) {
        float o[4];
        #pragma unroll
        for (int jj = 0; jj < 4; ++jj) o[jj] = acc[ii][jj] + b2s[tx * 4 + jj];
        *(float4*)&z[(size_t)(row0 + ty * 4 + ii) * HID + tx * 4] = *(float4*)&o[0];
    }
}

// ---------------- K7: sim = z1 @ z2^T (64x64 tiles, K=64) ----------------
__global__ __launch_bounds__(256) void sim_kernel(const float* __restrict__ z,
                                                  float* __restrict__ logits) {
    int bid = blockIdx.x;
    int b = bid >> 8;
    int tile = bid & 255;
    int ti = (tile >> 4) << 6;
    int tj = (tile & 15) << 6;
    const float* z1 = z + (size_t)b * NPTS * HID;
    const float* z2 = z + (size_t)(BATCH + b) * NPTS * HID;
    __shared__ float Z1[64][68];
    __shared__ float Z2[64][68];
    int tid = threadIdx.x;
    #pragma unroll
    for (int i = 0; i < 4; ++i) {
        int l = tid + i * 256;
        int r = l >> 4, c = (l & 15) * 4;
        *(float4*)&Z1[r][c] = *(const float4*)&z1[(size_t)(ti + r) * HID + c];
        *(float4*)&Z2[r][c] = *(const float4*)&z2[(size_t)(tj + r) * HID + c];
    }
    __syncthreads();
    int ty = tid >> 4, tx = tid & 15;
    float acc[4][4];
    #pragma unroll
    for (int i = 0; i < 4; ++i)
        #pragma unroll
        for (int j = 0; j < 4; ++j) acc[i][j] = 0.f;
    #pragma unroll
    for (int h = 0; h < HID; ++h) {
        float a[4], bb[4];
        #pragma unroll
        for (int ii = 0; ii < 4; ++ii) { a[ii] = Z1[ty * 4 + ii][h]; bb[ii] = Z2[tx * 4 + ii][h]; }
        #pragma unroll
        for (int ii = 0; ii < 4; ++ii)
            #pragma unroll
            for (int jj = 0; jj < 4; ++jj)
                acc[ii][jj] += a[ii] * bb[jj];
    }
    #pragma unroll
    for (int ii = 0; ii < 4; ++ii) {
        float* dst = logits + ((size_t)b * NPTS + ti + ty * 4 + ii) * NPTS + tj + tx * 4;
        *(float4*)&dst[0] = *(float4*)&acc[ii][0];
    }
}

// ---------------- K8: row softmax ----------------
__global__ __launch_bounds__(256) void softmax_kernel(const float* __restrict__ logits,
                                                      float* __restrict__ out) {
    int row = blockIdx.x;                         // 0..8191
    const float* L = logits + (size_t)row * NPTS;
    __shared__ float buf[NPTS];
    __shared__ float red[8];
    int tid = threadIdx.x;
    int wave = tid >> 6, lane = tid & 63;
    float mx = -3e38f;
    #pragma unroll
    for (int s = 0; s < 4; ++s) {
        float v = L[tid + s * 256];
        buf[tid + s * 256] = v;
        mx = fmaxf(mx, v);
    }
    #pragma unroll
    for (int off = 32; off > 0; off >>= 1) mx = fmaxf(mx, __shfl_down(mx, off));
    if (lane == 0) red[wave] = mx;
    __syncthreads();
    mx = fmaxf(fmaxf(red[0], red[1]), fmaxf(red[2], red[3]));
    float sum = 0.f;
    #pragma unroll
    for (int s = 0; s < 4; ++s) {
        float e = expf(buf[tid + s * 256] - mx);
        buf[tid + s * 256] = e;
        sum += e;
    }
    #pragma unroll
    for (int off = 32; off > 0; off >>= 1) sum += __shfl_down(sum, off);
    if (lane == 0) red[4 + wave] = sum;
    __syncthreads();
    float inv = 1.f / (red[4] + red[5] + red[6] + red[7]);
    #pragma unroll
    for (int s = 0; s < 4; ++s)
        out[(size_t)row * NPTS + tid + s * 256] = buf[tid + s * 256] * inv;
}

extern "C" void kernel_launch(void* const* d_in, const int* in_sizes, int n_in,
                              void* d_out, int out_size, void* d_ws, size_t ws_size,
                              hipStream_t stream) {
    const float* f1  = (const float*)d_in[0];
    const float* f2  = (const float*)d_in[1];
    const float* W1a = (const float*)d_in[2];
    const float* b1a = (const float*)d_in[3];
    const float* W2a = (const float*)d_in[4];
    const float* b2a = (const float*)d_in[5];
    const float* W1b = (const float*)d_in[6];
    const float* b1b = (const float*)d_in[7];
    const float* W2b = (const float*)d_in[8];
    const float* b2b = (const float*)d_in[9];
    float* out = (float*)d_out;

    // workspace: H packed (100.7MB) | dist (67.1MB, reused as sim logits) | sq | kidx | y | h1 | z
    char* ws = (char*)d_ws;
    unsigned short* H = (unsigned short*)ws;
    float* dist = (float*)(ws + (size_t)NMAT * NPTS * KPACK * sizeof(unsigned short));
    float* sq   = dist + (size_t)NMAT * NPTS * NPTS;
    int*   kidx = (int*)(sq + NMAT * NPTS);
    float* ybuf = (float*)(kidx + NMAT * NPTS * KNN);
    float* h1b  = ybuf + (size_t)NMAT * NPTS * HID;
    float* zb   = h1b + (size_t)NMAT * NPTS * HID;

    split_ymlp_kernel<<<NMAT * NPTS / 64, 256, 0, stream>>>(f1, f2, W1a, H, sq, ybuf);
    gram_mfma_kernel<<<NMAT * 36, 256, 0, stream>>>(H, sq, dist);
    topk_kernel<<<NMAT * NPTS / 4, 256, 0, stream>>>(dist, kidx);
    t1h1_kernel<<<NMAT * NPTS / 64, 256, 0, stream>>>(ybuf, kidx, W2a, b1a, b2a, h1b);
    t2z_kernel<<<NMAT * NPTS / 64, 256, 0, stream>>>(h1b, kidx, W1b, b1b, W2b, b2b, zb);
    sim_kernel<<<BATCH * 256, 256, 0, stream>>>(zb, dist);                      // dist := logits
    softmax_kernel<<<BATCH * NPTS, 256, 0, stream>>>(dist, out);
}